// Round 9
// baseline (284.215 us; speedup 1.0000x reference)
//
#include <hip/hip_runtime.h>
#include <hip/hip_bf16.h>

#define N_NODES 262144
#define NUM_C   256
#define DIM     128
#define NUM_G   128
#define GMAX    8
#define CHUNK_N 32                       // nodes per pipeline chunk
#define CHUNK_B (CHUNK_N * DIM * 4)      // 16384 B fp32
#define NCHUNK  8                        // 256 nodes per block

typedef short  bf16x8 __attribute__((ext_vector_type(8)));
typedef float  f32x4  __attribute__((ext_vector_type(4)));

__device__ __forceinline__ short f2b(float f) {
    __hip_bfloat16 h = __float2bfloat16(f);
    return *reinterpret_cast<short*>(&h);
}

// async global->LDS DMA, 16 B per lane.  Dest = wave-uniform LDS base +
// lane*16 (linear); source is per-lane (we pre-swizzle it).  Tracked by
// vmcnt; cannot be remat'd/sunk (r6/r8: plain & asm reg-loads both got
// defeated by the compiler; this holds no dest regs so there is nothing
// to defeat).
typedef const __attribute__((address_space(1))) unsigned int* gp1_t;
typedef __attribute__((address_space(3)))       unsigned int* lp3_t;
__device__ __forceinline__ void gld_lds16(const void* g, void* l) {
    __builtin_amdgcn_global_load_lds((gp1_t)g, (lp3_t)l, 16, 0, 0);
}

// ---------------------------------------------------------------------------
// Prep: zero out, convert W fp32->bf16 (row-major, unpadded), compute c_sq,
// build cum_end[g] from the sorted batch. Grid: 128 x 256. (verified r1/r2)
// ---------------------------------------------------------------------------
__global__ void centroid_prep(const float* __restrict__ W,
                              const int* __restrict__ batch,
                              float* __restrict__ out,
                              short* __restrict__ Wb,
                              float* __restrict__ csq,
                              int* __restrict__ cum_end)
{
    const int t   = threadIdx.x;
    const int b   = blockIdx.x;
    const int gid = b * 256 + t;

    float w = W[gid];
    out[gid] = 0.f;
    Wb[gid] = f2b(w);

    __shared__ float red[256];
    red[t] = w * w;
    __syncthreads();
    for (int off = 64; off > 0; off >>= 1) {
        if ((t & 127) < off) red[t] += red[t + off];
        __syncthreads();
    }
    if (t == 0)   csq[2 * b]     = red[0];
    if (t == 128) csq[2 * b + 1] = red[128];

    long i0 = (long)gid * 8;
    int g = batch[i0];
    if (gid == 0) {
        for (int gg = 0; gg < g; ++gg) cum_end[gg] = 0;
    }
    for (int k = 0; k < 8; ++k) {
        long i = i0 + k;
        int gn = (i + 1 < N_NODES) ? batch[i + 1] : NUM_G;
        if (gn != g) {
            for (int gg = g; gg < gn; ++gg) cum_end[gg] = (int)(i + 1);
        }
        g = gn;
    }
}

// ---------------------------------------------------------------------------
// Main, round-9: T3 2-phase with global_load_lds (the one pipelining
// mechanism the compiler can't delete).  1024 blocks x 512 threads, 256
// nodes/block in 8 chunks of 32.  Key facts driving this design:
//  * r8's L3-hot rocprof pass (0.65 MB HBM) ran the SAME 85-90 us as the
//    67-MB pass -> NOT bandwidth-bound; waves convoy on load latency with
//    compute idle (duty-cycle).  * r6/r8: reg-staged pipelines get deleted
//    (remat / allocation); gload_lds holds no dest regs -> pinned in flight
//    until the end-of-chunk barrier's vmcnt(0).
// Structure:
//  * B IN REGISTERS: wave = (node-group ng = wid&1: 16 nodes) x (centroid
//    quarter cq = wid>>1: 64 c).  b[4][4] = 64 VGPR loaded once from Wb.
//    Zero B ds_reads; W leaves LDS.
//  * x: 2 x 16 KB LDS dbuf, staged by gload_lds (2 insts/thread/chunk).
//    Stage k+1 issues BEFORE compute k; the only drain is the chunk-end
//    __syncthreads (T3 minimum 2-phase, 92% of 8-phase per guide).
//  * swizzle rule #21: LDS dest linear; per-lane GLOBAL source XOR'd with
//    (node&7)<<4 (bijective within each 512-B row, 16B-granular); A-reads
//    apply the same XOR -> bank spread on the fp32 reads.
//  * xsq computed once per wave per chunk, parked in a private LDS slot
//    (1 write + 1 b128 read; replaces 8 bpermutes); epilogue shuffle
//    reduce dropped (all 4 quads atomicAdd partials; 4-way same-address
//    LDS atomic ~ as cheap, no serial shfl latency).
// LDS 41.5 KB -> 2 blocks/CU; __launch_bounds__(512,2) -> 128-VGPR budget
// (2nd arg = blocks/CU, r1-r3); est live ~115.
// dist = sqrt(max(xsq + csq - 2*cross, 0)); pooled into lacc -> atomics.
// ---------------------------------------------------------------------------
__global__ __launch_bounds__(512, 2) void centroid_main(
    const float* __restrict__ x,
    const int* __restrict__ batch,
    const short* __restrict__ Wb,
    const float* __restrict__ csq,
    float* __restrict__ out)
{
    __shared__ __align__(16) char  xb[2 * CHUNK_B];   // 32768 B, fp32 swizzled
    __shared__ float lacc[GMAX * NUM_C];              //  8192 B
    __shared__ float xsql[8 * 16];                    //   512 B

    const int t    = threadIdx.x;
    const int nb   = blockIdx.x << 8;        // 256 nodes per block
    const int lane = t & 63;
    const int m16  = lane & 15;
    const int quad = lane >> 4;
    const int wid  = t >> 6;                 // 0..7
    const int ng   = wid & 1;                // node-group (16 nodes)
    const int cq   = wid >> 1;               // centroid-quarter (64 c)

#define STAGE_CHUNK(k_, buf_) do {                                         \
    _Pragma("unroll")                                                      \
    for (int i_ = 0; i_ < 2; ++i_) {                                       \
        const int o_  = wid * 2048 + i_ * 1024 + lane * 16;                \
        const int nd_ = o_ >> 9;                                           \
        const int r_  = o_ & 511;                                          \
        const char* g_ = (const char*)x +                                  \
            (((long)(nb + (k_) * CHUNK_N + nd_)) << 9) +                   \
            (r_ ^ ((nd_ & 7) << 4));                                       \
        gld_lds16(g_, (char*)xb + (buf_) * CHUNK_B + wid * 2048 + i_ * 1024); \
    } } while (0)

    // ---- issue chunk-0 staging immediately (flies during setup) ----
    STAGE_CHUNK(0, 0);

    // ---- B fragments: 4 ct x 4 ks in 64 VGPRs, loaded once (L2-hot) ----
    bf16x8 b[4][4];
    float  csr[4];
#pragma unroll
    for (int ct = 0; ct < 4; ++ct) {
        const short* wr = Wb + (cq * 64 + ct * 16 + m16) * DIM + quad * 8;
#pragma unroll
        for (int ks = 0; ks < 4; ++ks)
            b[ct][ks] = *(const bf16x8*)(wr + ks * 32);
        csr[ct] = csq[cq * 64 + ct * 16 + m16];
    }

    for (int i = t; i < GMAX * NUM_C; i += 512) lacc[i] = 0.f;

    const int  gmin    = batch[nb];
    const int  span    = batch[nb + 255] - gmin + 1;
    const bool use_lds = (span <= GMAX);

    __syncthreads();   // vmcnt(0): chunk0 landed; lacc zero visible

    // ---- 2-phase chunk loop: stage k+1, compute k, barrier ----
#pragma unroll 1
    for (int k = 0; k < NCHUNK; ++k) {
        if (k + 1 < NCHUNK) STAGE_CHUNK(k + 1, (k + 1) & 1);

        const char* xl = (const char*)xb + (k & 1) * CHUNK_B;
        const int   nd = ng * 16 + m16;      // this lane's node row (local)
        const int   sw = (nd & 7) << 4;

        // A fragments (fp32 from LDS, swizzled) + row sum-of-squares
        float  ss = 0.f;
        bf16x8 af[4];
#pragma unroll
        for (int ks = 0; ks < 4; ++ks) {
            const int ro = quad * 32 + ks * 128;
            f32x4 u0 = *(const f32x4*)(xl + nd * 512 + ((ro)      ^ sw));
            f32x4 u1 = *(const f32x4*)(xl + nd * 512 + ((ro + 16) ^ sw));
            bf16x8 av;
#pragma unroll
            for (int j = 0; j < 4; ++j) {
                ss += u0[j] * u0[j] + u1[j] * u1[j];
                av[j]     = f2b(u0[j]);
                av[j + 4] = f2b(u1[j]);
            }
            af[ks] = av;
        }
        ss += __shfl_xor(ss, 16);
        ss += __shfl_xor(ss, 32);
        if (lane < 16) xsql[wid * 16 + m16] = ss;     // wave-private slot
        const f32x4 pre4 = *(const f32x4*)&xsql[wid * 16 + quad * 4];

        const int  bnode = nb + k * CHUNK_N + ng * 16;
        const int  g0    = batch[bnode];
        const bool uni   = (g0 == batch[bnode + 15]);

#pragma unroll
        for (int ct = 0; ct < 4; ++ct) {
            f32x4 acc = {0.f, 0.f, 0.f, 0.f};
            acc = __builtin_amdgcn_mfma_f32_16x16x32_bf16(af[0], b[ct][0], acc, 0, 0, 0);
            acc = __builtin_amdgcn_mfma_f32_16x16x32_bf16(af[1], b[ct][1], acc, 0, 0, 0);
            acc = __builtin_amdgcn_mfma_f32_16x16x32_bf16(af[2], b[ct][2], acc, 0, 0, 0);
            acc = __builtin_amdgcn_mfma_f32_16x16x32_bf16(af[3], b[ct][3], acc, 0, 0, 0);

            const int   c  = cq * 64 + ct * 16 + m16;
            const float cs = csr[ct];

            if (use_lds && uni) {
                float v = 0.f;
#pragma unroll
                for (int r = 0; r < 4; ++r) {
                    float d2 = __builtin_fmaf(acc[r], -2.f, pre4[r] + cs);
                    v += __builtin_amdgcn_sqrtf(__builtin_fmaxf(d2, 0.f));
                }
                atomicAdd(&lacc[(g0 - gmin) * NUM_C + c], v);   // 4-way same-addr
            } else {
#pragma unroll
                for (int r = 0; r < 4; ++r) {
                    float d2 = __builtin_fmaf(acc[r], -2.f, pre4[r] + cs);
                    float d  = __builtin_amdgcn_sqrtf(__builtin_fmaxf(d2, 0.f));
                    int   g  = uni ? g0 : batch[bnode + quad * 4 + r];
                    if (use_lds) atomicAdd(&lacc[(g - gmin) * NUM_C + c], d);
                    else         atomicAdd(&out[g * NUM_C + c], d);
                }
            }
        }

        __syncthreads();   // vmcnt(0): chunk k+1 landed; buf k&1 reads done
    }

    if (use_lds) {
        for (int i = t; i < span * NUM_C; i += 512)
            atomicAdd(&out[(gmin + (i >> 8)) * NUM_C + (i & 255)], lacc[i]);
    }
#undef STAGE_CHUNK
}

// ---------------------------------------------------------------------------
// Finish: divide sums by per-graph counts. Grid: 128 x 256.
// ---------------------------------------------------------------------------
__global__ void centroid_finish(float* __restrict__ out,
                                const int* __restrict__ cum_end)
{
    const int g = blockIdx.x;
    const int c = threadIdx.x;
    int cnt = cum_end[g] - (g ? cum_end[g - 1] : 0);
    float denom = (float)(cnt > 0 ? cnt : 1);
    out[g * NUM_C + c] /= denom;
}

extern "C" void kernel_launch(void* const* d_in, const int* in_sizes, int n_in,
                              void* d_out, int out_size, void* d_ws, size_t ws_size,
                              hipStream_t stream) {
    const float* x     = (const float*)d_in[0];
    const int*   batch = (const int*)d_in[1];
    const float* W     = (const float*)d_in[2];
    float*       out   = (float*)d_out;

    // workspace: Wb (64 KB) | csq (1 KB) | cum_end (512 B)
    short* Wb      = (short*)d_ws;
    float* csq     = (float*)((char*)d_ws + 65536);
    int*   cum_end = (int*)((char*)d_ws + 65536 + 1024);

    centroid_prep<<<128, 256, 0, stream>>>(W, batch, out, Wb, csq, cum_end);
    centroid_main<<<N_NODES / 256, 512, 0, stream>>>(x, batch, Wb, csq, out);
    centroid_finish<<<NUM_G, 256, 0, stream>>>(out, cum_end);
}